// Round 5
// baseline (474.475 us; speedup 1.0000x reference)
//
#include <hip/hip_runtime.h>

typedef unsigned short u16;
typedef unsigned int u32;

#define B_   64
#define C_   256
#define L_   4096
#define NH   8
#define NQ   16
#define DH   32
#define HQ   128
#define FHN  512
#define EPS_ 1e-6f

// ---- workspace layout (bytes), ~10.1 MB ----
#define WS_WC    0            // u16 [128][32]               8192
#define WS_SWG   8192         // f32 [128]                    512
#define WS_CB    8704         // f32 [128]                    512
#define WS_VGC   9216         // u16 [256][256]            131072
#define WS_WG1   140288       // f32 [256]                   1024
#define WS_WB1   141312       // f32 [256]                   1024
#define WS_DENP  142336       // f32 [8][8192]             262144
#define WS_SNUP  404480       // f32 [8][8192]             262144
#define WS_A     666624       // f32 [64][128][32]        1048576
#define WS_APART 1715200      // f32 [8][64][128][32]     8388608

typedef __attribute__((ext_vector_type(8))) short bf16x8;
typedef __attribute__((ext_vector_type(4))) float f32x4;

__device__ __forceinline__ u16 f32_to_bf16(float f) {
    u32 u = __float_as_uint(f);
    u32 r = u + 0x7fffu + ((u >> 16) & 1u);   // RNE
    return (u16)(r >> 16);
}
__device__ __forceinline__ float bf16_to_f32(u16 h) {
    return __uint_as_float(((u32)h) << 16);
}
__device__ __forceinline__ u32 pk2(u16 lo, u16 hi) {
    return (u32)lo | ((u32)hi << 16);
}

// ---------------------------------------------------------------------------
// k_prep: wc[hq][32] = bf16(attn_w * gamma_slice); Swg = sum of the bf16 vals
// (fp32) so the mu-correction matches the MFMA operand exactly; Cb = w.beta.
// ---------------------------------------------------------------------------
__global__ __launch_bounds__(256) void k_prep(
    const float* __restrict__ attn_w, const float* __restrict__ gamma,
    const float* __restrict__ beta, u16* __restrict__ wc,
    float* __restrict__ Swg, float* __restrict__ Cb)
{
    int t = threadIdx.x;
    if (t >= HQ) return;
    int h = t >> 4;
    float sw = 0.f, cb = 0.f;
    for (int c = 0; c < DH; c++) {
        float w = attn_w[t * DH + c];
        u16 hb = f32_to_bf16(w * gamma[h * DH + c]);
        wc[t * DH + c] = hb;
        sw += bf16_to_f32(hb);
        cb += w * beta[h * DH + c];
    }
    Swg[t] = sw;
    Cb[t] = cb;
}

// ---------------------------------------------------------------------------
// k_prepv: VGc[e][c] = bf16(val_w[e][c]*gamma[c]) for the epilogue MFMA;
// Wg1[e] = sum_c of the bf16 values (exact mu-cancellation), Wb1[e] = w.beta.
// ---------------------------------------------------------------------------
__global__ __launch_bounds__(256) void k_prepv(
    const float* __restrict__ val_w, const float* __restrict__ gamma,
    const float* __restrict__ beta, u16* __restrict__ VGc,
    float* __restrict__ Wg1, float* __restrict__ Wb1)
{
    int t = threadIdx.x;
    int e = blockIdx.x * 4 + (t >> 6);
    int lane = t & 63;
    float4 w  = *(const float4*)(val_w + (size_t)e * C_ + lane * 4);
    float4 g  = *(const float4*)(gamma + lane * 4);
    float4 bt = *(const float4*)(beta + lane * 4);
    u16 h0 = f32_to_bf16(w.x * g.x);
    u16 h1 = f32_to_bf16(w.y * g.y);
    u16 h2 = f32_to_bf16(w.z * g.z);
    u16 h3 = f32_to_bf16(w.w * g.w);
    uint2 pk;
    pk.x = pk2(h0, h1);
    pk.y = pk2(h2, h3);
    *(uint2*)(VGc + (size_t)e * C_ + lane * 4) = pk;
    float sg = bf16_to_f32(h0) + bf16_to_f32(h1) + bf16_to_f32(h2) + bf16_to_f32(h3);
    float sb = w.x * bt.x + w.y * bt.y + w.z * bt.z + w.w * bt.w;
    #pragma unroll
    for (int off = 1; off < 64; off <<= 1) {
        sg += __shfl_xor(sg, off);
        sb += __shfl_xor(sb, off);
    }
    if (lane == 0) { Wg1[e] = sg; Wb1[e] = sb; }
}

// ---------------------------------------------------------------------------
// k_fused v5 = R1 chassis (4 waves, 256 thr, grid (8,64)) + COALESCED staging.
// x load: lane-groups of 8 read one channel-row (128 B contiguous) -> 8 fully
// consumed cache lines per wave-load (R1 was 64 partial lines: lane-per-channel
// at 16 KB stride). [l][c] tile (XT) produced by in-register 4x4 bf16
// transpose (2 shfl_xor rounds); XC b64 writes swizzle-compatible with the
// unchanged GEMM reads. Both LDS write patterns are at the 4-words/bank b64
// minimum (conflict-free). Everything downstream bit-identical to R1.
// __launch_bounds__(256,2): 256-thr blocks make the 2nd arg unambiguous
// (= blocks/CU = waves/EU here) -> 256-VGPR cap, no spill (R2/R4 trap).
// ---------------------------------------------------------------------------
__global__ __launch_bounds__(256, 2) void k_fused(
    const float* __restrict__ x, const u16* __restrict__ wc,
    const float* __restrict__ Swg, const float* __restrict__ Cb,
    const u16* __restrict__ VGc, float* __restrict__ Apart,
    float* __restrict__ DenP, float* __restrict__ SnuP)
{
    // pool: main loop {XT 16896 | EA 10240 | XC 32768} = 59904 B
    //       epilogue  {P_lds 128*264*2 = 67584 B}
    __shared__ __align__(16) char POOL[67584];
    u16* const XT  = (u16*)POOL;            // [32][264]
    u16* const EA  = (u16*)(POOL + 16896);  // [128][40]
    u16* const XCb = (u16*)(POOL + 27136);  // [2][256*32] swizzled
    __shared__ float smu[32], srs[32];
    int t = threadIdx.x;
    int lane = t & 63, wv = t >> 6;
    int lane15 = lane & 15, quad = lane >> 4;
    int ks = blockIdx.x, b = blockIdx.y;
    int lbase = ks * 512;
    int m0 = (wv & 1) * 64, n0 = (wv >> 1) * 128;

    // staging geometry: lv = l-quad (l = 4*lv..4*lv+3), rw = channel row
    int lv = t & 7, rw = t >> 3;
    int ti = rw & 3;              // transpose quad index (column id)
    int cbase = rw & ~3;          // channel quad base (within pass)

    // logits constants: per wave 2 heads, A-frags + Swg/Cb in registers
    bf16x8 af[2];
    float swr[2][4], cbr[2][4];
    #pragma unroll
    for (int s = 0; s < 2; s++) {
        int h = wv * 2 + s;
        af[s] = *(const bf16x8*)(wc + (size_t)(h * 16 + lane15) * DH + quad * 8);
        #pragma unroll
        for (int r = 0; r < 4; r++) {
            int hq = h * 16 + quad * 4 + r;
            swr[s][r] = Swg[hq];
            cbr[s][r] = Cb[hq];
        }
    }

    // coalesced base: 8 consecutive lanes cover one channel-row's 128 B
    const float* xB = x + (size_t)b * C_ * L_ + lbase + lv * 4;

    float4 fr[8];       // fp32 prefetch: pass p -> channel p*32+rw, l=4lv..+3
    uint2 pr2[8];       // packed bf16 (4 l per pass); transposed in-place
    auto loadregs = [&](int k) {
        #pragma unroll
        for (int p = 0; p < 8; p++)
            fr[p] = *(const float4*)(xB + (size_t)(p * 32 + rw) * L_ + k * 32);
    };
    auto cvtregs = [&]() {
        #pragma unroll
        for (int p = 0; p < 8; p++) {
            pr2[p].x = pk2(f32_to_bf16(fr[p].x), f32_to_bf16(fr[p].y));
            pr2[p].y = pk2(f32_to_bf16(fr[p].z), f32_to_bf16(fr[p].w));
        }
    };
    // XC[c][l] (swizzled 16-B granules, same mapping the GEMM reads)
    auto write_xc = [&](int buf) {
        int g2 = lv >> 1, hl = (lv & 1) * 4;
        #pragma unroll
        for (int p = 0; p < 8; p++) {
            int c = p * 32 + rw;
            *(uint2*)&XCb[buf * 8192 + c * 32 + ((g2 ^ (c & 3)) * 8) + hl] = pr2[p];
        }
    };
    // 4x4 bf16 transpose across lanes {ti, ti^1, ti^2, ti^3} (stride-8 ids):
    // before: lane holds (channel cbase+ti, l = 4lv..4lv+3)
    // after:  lane holds (l = 4lv+ti, channels cbase..cbase+3)
    auto transpose_pr = [&]() {
        #pragma unroll
        for (int p = 0; p < 8; p++) {
            u32 a = pr2[p].x, bq = pr2[p].y;
            u32 ta = __shfl_xor(a, 16);
            u32 tb = __shfl_xor(bq, 16);
            u32 A1 = (ti & 2) ? tb : a;     // rows pair, col (ti&1)
            u32 B1 = (ti & 2) ? bq : ta;    // rows pair, col (ti&1)+2
            u32 pA = __shfl_xor(A1, 8);
            u32 pB = __shfl_xor(B1, 8);
            u32 Af, Bf;
            if ((ti & 1) == 0) {
                Af = (A1 & 0xffffu) | (pA << 16);
                Bf = (B1 & 0xffffu) | (pB << 16);
            } else {
                Af = (pA >> 16) | (A1 & 0xffff0000u);
                Bf = (pB >> 16) | (B1 & 0xffff0000u);
            }
            pr2[p].x = Af;
            pr2[p].y = Bf;
        }
    };
    auto write_xt = [&]() {
        int l = 4 * lv + ti;
        #pragma unroll
        for (int p = 0; p < 8; p++)
            *(uint2*)&XT[l * 264 + p * 32 + cbase] = pr2[p];
    };

    f32x4 acc[4][8];
    #pragma unroll
    for (int i = 0; i < 4; i++)
        #pragma unroll
        for (int j = 0; j < 8; j++) {
            f32x4 z = {0.f, 0.f, 0.f, 0.f};
            acc[i][j] = z;
        }
    float se[2][4] = {}, sm[2][4] = {};

    int l_loc = t >> 3, g = t & 7;     // stats assignment: 8 threads per l

    loadregs(0);
    cvtregs();
    write_xc(0);
    transpose_pr();
    write_xt();
    loadregs(1);
    __syncthreads();

    for (int k = 0; k < 16; k++) {
        int cur = k & 1;

        // ---- stats phase: mu/rs for chunk k from XT (bf16-sourced) ----
        {
            const u16* row = XT + l_loc * 264 + g * 32;
            float s = 0.f, q = 0.f;
            #pragma unroll
            for (int j = 0; j < 4; j++) {
                uint4 v = *(const uint4*)(row + j * 8);
                u32 ww[4] = {v.x, v.y, v.z, v.w};
                #pragma unroll
                for (int e = 0; e < 4; e++) {
                    float f0 = __uint_as_float(ww[e] << 16);
                    float f1 = __uint_as_float(ww[e] & 0xffff0000u);
                    s += f0 + f1;
                    q += f0 * f0 + f1 * f1;
                }
            }
            #pragma unroll
            for (int off = 1; off < 8; off <<= 1) {
                s += __shfl_xor(s, off);
                q += __shfl_xor(q, off);
            }
            if (g == 0) {
                float mm = s * (1.f / C_);
                float vv = fmaxf(q * (1.f / C_) - mm * mm, 0.f) + EPS_;
                smu[l_loc] = mm;
                srs[l_loc] = rsqrtf(vv);
            }
        }
        __syncthreads();   // smu/srs ready

        // ---- logits phase: MFMA over XT -> exp -> EA (+ running sums) ----
        #pragma unroll
        for (int half = 0; half < 2; half++) {
            float m_l = smu[half * 16 + lane15];
            float r_l = srs[half * 16 + lane15];
            #pragma unroll
            for (int s = 0; s < 2; s++) {
                int h = wv * 2 + s;
                bf16x8 bfrag = *(const bf16x8*)(XT + (half * 16 + lane15) * 264 + h * DH + quad * 8);
                f32x4 z = {0.f, 0.f, 0.f, 0.f};
                f32x4 c4 = __builtin_amdgcn_mfma_f32_16x16x32_bf16(af[s], bfrag, z, 0, 0, 0);
                #pragma unroll
                for (int r = 0; r < 4; r++) {
                    float logit = r_l * (c4[r] - m_l * swr[s][r]) + cbr[s][r];
                    float e = __expf(logit);     // logits ~N(0,1): no max-sub needed
                    float ers = e * r_l;
                    EA[(h * 16 + quad * 4 + r) * 40 + half * 16 + lane15] = f32_to_bf16(ers);
                    se[s][r] += e;
                    sm[s][r] += ers * m_l;
                }
            }
        }
        __syncthreads();   // EA complete; XT reads done -> XT free

        // ---- staging for chunk k+1 + GEMM chunk k ----
        if (k < 15) { cvtregs(); write_xc(cur ^ 1); transpose_pr(); write_xt(); }
        if (k < 14) loadregs(k + 2);

        bf16x8 a[4];
        #pragma unroll
        for (int i = 0; i < 4; i++)
            a[i] = *(const bf16x8*)&EA[(m0 + i * 16 + lane15) * 40 + quad * 8];
        #pragma unroll
        for (int j = 0; j < 8; j++) {
            int row = n0 + j * 16 + lane15;
            bf16x8 bbj = *(const bf16x8*)&XCb[cur * 8192 + row * 32 + ((quad ^ (row & 3)) * 8)];
            #pragma unroll
            for (int i = 0; i < 4; i++)
                acc[i][j] = __builtin_amdgcn_mfma_f32_16x16x32_bf16(a[i], bbj, acc[i][j], 0, 0, 0);
        }
        __syncthreads();   // GEMM reads done -> EA/XC[cur] free for next iter
    }

    // ---- epilogue 1: Praw (acc) -> LDS bf16 [hq][c], pitch 264 ----
    u16* const P = (u16*)POOL;   // reuses the whole pool (all readers done)
    #pragma unroll
    for (int i = 0; i < 4; i++)
        #pragma unroll
        for (int j = 0; j < 8; j++) {
            int row = m0 + i * 16 + quad * 4;
            int col = n0 + j * 16 + lane15;
            #pragma unroll
            for (int r = 0; r < 4; r++)
                P[(row + r) * 264 + col] = f32_to_bf16(acc[i][j][r]);
        }
    __syncthreads();

    // ---- epilogue 2: Apart[hq][d] = sum_c VGc[hd][c] * Praw[hq][c] ----
    float* ApB = Apart + (((size_t)ks * B_ + b) * HQ) * DH;
    #pragma unroll
    for (int s = 0; s < 2; s++) {
        int h = wv * 2 + s;
        #pragma unroll
        for (int dt = 0; dt < 2; dt++) {
            f32x4 c2 = {0.f, 0.f, 0.f, 0.f};
            #pragma unroll
            for (int kk = 0; kk < 8; kk++) {
                bf16x8 a = *(const bf16x8*)&P[(h * 16 + lane15) * 264 + kk * 32 + quad * 8];
                bf16x8 vg = *(const bf16x8*)(VGc + (size_t)(h * DH + dt * 16 + lane15) * C_ + kk * 32 + quad * 8);
                c2 = __builtin_amdgcn_mfma_f32_16x16x32_bf16(a, vg, c2, 0, 0, 0);
            }
            #pragma unroll
            for (int r = 0; r < 4; r++)
                ApB[(size_t)(h * 16 + quad * 4 + r) * DH + dt * 16 + lane15] = c2[r];
        }
    }

    // ---- softmax partial sums: reduce over lane15, one plain store per row ----
    #pragma unroll
    for (int s = 0; s < 2; s++)
        #pragma unroll
        for (int r = 0; r < 4; r++) {
            float v = se[s][r], w = sm[s][r];
            #pragma unroll
            for (int off = 1; off < 16; off <<= 1) {
                v += __shfl_xor(v, off);
                w += __shfl_xor(w, off);
            }
            if (lane15 == 0) {
                int row = b * HQ + (wv * 2 + s) * 16 + quad * 4 + r;
                DenP[ks * (B_ * HQ) + row] = v;
                SnuP[ks * (B_ * HQ) + row] = w;
            }
        }
}

// ---------------------------------------------------------------------------
// k_reduce: A[b][hq][d] = (sum_s Apart - SnuTot*Wg1[hd]) / DenTot
//           + Wb1[hd] + val_b[hd]       (beta term: se/den == 1)
// ---------------------------------------------------------------------------
__global__ __launch_bounds__(256) void k_reduce(
    const float* __restrict__ Apart, const float* __restrict__ DenP,
    const float* __restrict__ SnuP, const float* __restrict__ Wg1,
    const float* __restrict__ Wb1, const float* __restrict__ val_b,
    float* __restrict__ A)
{
    __shared__ float sden[32], ssnu[32];
    int t = threadIdx.x;
    int q4 = blockIdx.x, b = blockIdx.y;
    int hq0 = q4 * 32;
    if (t < 32) {
        int row = b * HQ + hq0 + t;
        float d = 0.f, sn = 0.f;
        #pragma unroll
        for (int s = 0; s < 8; s++) {
            d  += DenP[s * (B_ * HQ) + row];
            sn += SnuP[s * (B_ * HQ) + row];
        }
        sden[t] = d;
        ssnu[t] = sn;
    }
    __syncthreads();
    #pragma unroll
    for (int i = 0; i < 4; i++) {
        int idx = i * 256 + t;
        int r32 = idx >> 5, d = idx & 31;
        int hq = hq0 + r32;
        float v = 0.f;
        #pragma unroll
        for (int s = 0; s < 8; s++)
            v += Apart[(((size_t)s * B_ + b) * HQ + hq) * DH + d];
        int hd = (hq >> 4) * DH + d;
        A[((size_t)b * HQ + hq) * DH + d] =
            (v - ssnu[r32] * Wg1[hd]) / sden[r32] + Wb1[hd] + val_b[hd];
    }
}

// ---------------------------------------------------------------------------
// k_final: out[b][f] = sum_j A[b][j]*fin_w[f][j] + fin_b[f]
// grid (32,16), block 256; k-split atomicAdd (out pre-zeroed).
// ---------------------------------------------------------------------------
__global__ __launch_bounds__(256) void k_final(
    const float* __restrict__ A, const float* __restrict__ fin_w,
    const float* __restrict__ fin_b, float* __restrict__ out)
{
    __shared__ float At[64 * 129];
    __shared__ float Fw[32 * 129];
    int t = threadIdx.x;
    int kc = blockIdx.x, ft = blockIdx.y;
    int k0 = kc * 128;

    #pragma unroll
    for (int w = 0; w < 8; w++) {
        int s = t + w * 256;
        int row = s >> 5, seg = s & 31;
        float4 v = *(const float4*)(A + (size_t)row * 4096 + k0 + seg * 4);
        const float* pf = (const float*)&v;
        #pragma unroll
        for (int e = 0; e < 4; e++) At[row * 129 + seg * 4 + e] = pf[e];
    }
    #pragma unroll
    for (int w = 0; w < 4; w++) {
        int s = t + w * 256;
        int row = s >> 5, seg = s & 31;
        float4 v = *(const float4*)(fin_w + (size_t)(ft * 32 + row) * 4096 + k0 + seg * 4);
        const float* pf = (const float*)&v;
        #pragma unroll
        for (int e = 0; e < 4; e++) Fw[row * 129 + seg * 4 + e] = pf[e];
    }
    __syncthreads();

    int tb = t >> 3, tf = t & 7;
    float acc[2][4];
    #pragma unroll
    for (int e = 0; e < 2; e++)
        #pragma unroll
        for (int j = 0; j < 4; j++) acc[e][j] = 0.f;

    for (int k = 0; k < 128; k++) {
        float a0 = At[(tb * 2) * 129 + k];
        float a1 = At[(tb * 2 + 1) * 129 + k];
        #pragma unroll
        for (int j = 0; j < 4; j++) {
            float f = Fw[(tf * 4 + j) * 129 + k];
            acc[0][j] += a0 * f;
            acc[1][j] += a1 * f;
        }
    }
    #pragma unroll
    for (int e = 0; e < 2; e++) {
        int brow = tb * 2 + e;
        #pragma unroll
        for (int j = 0; j < 4; j++) {
            int f = ft * 32 + tf * 4 + j;
            float v = acc[e][j];
            if (kc == 0) v += fin_b[f];
            atomicAdd(&out[(size_t)brow * FHN + f], v);
        }
    }
}

extern "C" void kernel_launch(void* const* d_in, const int* in_sizes, int n_in,
                              void* d_out, int out_size, void* d_ws, size_t ws_size,
                              hipStream_t stream) {
    const float* x      = (const float*)d_in[0];
    const float* gamma  = (const float*)d_in[1];
    const float* beta   = (const float*)d_in[2];
    const float* attn_w = (const float*)d_in[3];
    const float* val_w  = (const float*)d_in[4];
    const float* val_b  = (const float*)d_in[5];
    const float* fin_w  = (const float*)d_in[6];
    const float* fin_b  = (const float*)d_in[7];
    float* out = (float*)d_out;
    char* ws = (char*)d_ws;

    u16*   wc    = (u16*)(ws + WS_WC);
    float* Swg   = (float*)(ws + WS_SWG);
    float* Cb    = (float*)(ws + WS_CB);
    u16*   VGc   = (u16*)(ws + WS_VGC);
    float* Wg1   = (float*)(ws + WS_WG1);
    float* Wb1   = (float*)(ws + WS_WB1);
    float* DenP  = (float*)(ws + WS_DENP);
    float* SnuP  = (float*)(ws + WS_SNUP);
    float* A     = (float*)(ws + WS_A);
    float* Apart = (float*)(ws + WS_APART);

    hipMemsetAsync(out, 0, (size_t)B_ * FHN * sizeof(float), stream);

    k_prep<<<dim3(1), dim3(256), 0, stream>>>(attn_w, gamma, beta, wc, Swg, Cb);
    k_prepv<<<dim3(64), dim3(256), 0, stream>>>(val_w, gamma, beta, VGc, Wg1, Wb1);
    k_fused<<<dim3(8, 64), dim3(256), 0, stream>>>(x, wc, Swg, Cb, VGc, Apart,
                                                   DenP, SnuP);
    k_reduce<<<dim3(4, 64), dim3(256), 0, stream>>>(Apart, DenP, SnuP, Wg1, Wb1,
                                                    val_b, A);
    k_final<<<dim3(32, 16), dim3(256), 0, stream>>>(A, fin_w, fin_b, out);
}

// Round 6
// 428.840 us; speedup vs baseline: 1.1064x; 1.1064x over previous
//
#include <hip/hip_runtime.h>

typedef unsigned short u16;
typedef unsigned int u32;

#define B_   64
#define C_   256
#define L_   4096
#define NH   8
#define NQ   16
#define DH   32
#define HQ   128
#define FHN  512
#define EPS_ 1e-6f

// ---- workspace layout (bytes), ~10.1 MB ----
#define WS_WC    0            // u16 [128][32]               8192
#define WS_SWG   8192         // f32 [128]                    512
#define WS_CB    8704         // f32 [128]                    512
#define WS_VGC   9216         // u16 [256][256]            131072
#define WS_WG1   140288       // f32 [256]                   1024
#define WS_WB1   141312       // f32 [256]                   1024
#define WS_DENP  142336       // f32 [8][8192]             262144
#define WS_SNUP  404480       // f32 [8][8192]             262144
#define WS_A     666624       // f32 [64][128][32]        1048576
#define WS_APART 1715200      // f32 [8][64][128][32]     8388608

typedef __attribute__((ext_vector_type(8))) short bf16x8;
typedef __attribute__((ext_vector_type(4))) float f32x4;

__device__ __forceinline__ u16 f32_to_bf16(float f) {
    u32 u = __float_as_uint(f);
    u32 r = u + 0x7fffu + ((u >> 16) & 1u);   // RNE
    return (u16)(r >> 16);
}
__device__ __forceinline__ float bf16_to_f32(u16 h) {
    return __uint_as_float(((u32)h) << 16);
}
__device__ __forceinline__ u32 pk2(u16 lo, u16 hi) {
    return (u32)lo | ((u32)hi << 16);
}

// ---------------------------------------------------------------------------
// k_prep: wc[hq][32] = bf16(attn_w * gamma_slice); Swg = sum of the bf16 vals
// (fp32) so the mu-correction matches the MFMA operand exactly; Cb = w.beta.
// ---------------------------------------------------------------------------
__global__ __launch_bounds__(256) void k_prep(
    const float* __restrict__ attn_w, const float* __restrict__ gamma,
    const float* __restrict__ beta, u16* __restrict__ wc,
    float* __restrict__ Swg, float* __restrict__ Cb)
{
    int t = threadIdx.x;
    if (t >= HQ) return;
    int h = t >> 4;
    float sw = 0.f, cb = 0.f;
    for (int c = 0; c < DH; c++) {
        float w = attn_w[t * DH + c];
        u16 hb = f32_to_bf16(w * gamma[h * DH + c]);
        wc[t * DH + c] = hb;
        sw += bf16_to_f32(hb);
        cb += w * beta[h * DH + c];
    }
    Swg[t] = sw;
    Cb[t] = cb;
}

// ---------------------------------------------------------------------------
// k_prepv: VGc[e][c] = bf16(val_w[e][c]*gamma[c]) for the epilogue MFMA;
// Wg1[e] = sum_c of the bf16 values (exact mu-cancellation), Wb1[e] = w.beta.
// ---------------------------------------------------------------------------
__global__ __launch_bounds__(256) void k_prepv(
    const float* __restrict__ val_w, const float* __restrict__ gamma,
    const float* __restrict__ beta, u16* __restrict__ VGc,
    float* __restrict__ Wg1, float* __restrict__ Wb1)
{
    int t = threadIdx.x;
    int e = blockIdx.x * 4 + (t >> 6);
    int lane = t & 63;
    float4 w  = *(const float4*)(val_w + (size_t)e * C_ + lane * 4);
    float4 g  = *(const float4*)(gamma + lane * 4);
    float4 bt = *(const float4*)(beta + lane * 4);
    u16 h0 = f32_to_bf16(w.x * g.x);
    u16 h1 = f32_to_bf16(w.y * g.y);
    u16 h2 = f32_to_bf16(w.z * g.z);
    u16 h3 = f32_to_bf16(w.w * g.w);
    uint2 pk;
    pk.x = pk2(h0, h1);
    pk.y = pk2(h2, h3);
    *(uint2*)(VGc + (size_t)e * C_ + lane * 4) = pk;
    float sg = bf16_to_f32(h0) + bf16_to_f32(h1) + bf16_to_f32(h2) + bf16_to_f32(h3);
    float sb = w.x * bt.x + w.y * bt.y + w.z * bt.z + w.w * bt.w;
    #pragma unroll
    for (int off = 1; off < 64; off <<= 1) {
        sg += __shfl_xor(sg, off);
        sb += __shfl_xor(sb, off);
    }
    if (lane == 0) { Wg1[e] = sg; Wb1[e] = sb; }
}

// ---------------------------------------------------------------------------
// k_fused v6 = R1 compute path (3-phase, dbuf XC, scalar XT stores, NO
// cross-lane transpose) + R5 coalesced loads.
// Staging geometry: thread owns (8 channels x 4 l) per chunk instead of
// (1 channel x 32 l): per wave-load, 8 channel-rows x 128 B contiguous
// -> 16 cache lines / 8 DRAM rows (R1: 64 lines in 64 rows -> DRAM
// row-activate bound, the ~150us plateau). XT built with 32 scalar u16
// stores (same count as R1); XC with uint2 stores into the same swizzled
// granule layout the GEMM reads (2-way = free). LDS contents byte-identical
// to R1 => identical numerics downstream.
// ---------------------------------------------------------------------------
__global__ __launch_bounds__(256) void k_fused(
    const float* __restrict__ x, const u16* __restrict__ wc,
    const float* __restrict__ Swg, const float* __restrict__ Cb,
    const u16* __restrict__ VGc, float* __restrict__ Apart,
    float* __restrict__ DenP, float* __restrict__ SnuP)
{
    // pool: main loop {XT 16896 | EA 10240 | XC 32768} = 59904 B
    //       epilogue  {P_lds 128*264*2 = 67584 B}
    __shared__ __align__(16) char POOL[67584];
    u16* const XT  = (u16*)POOL;            // [32][264]
    u16* const EA  = (u16*)(POOL + 16896);  // [128][40]
    u16* const XCb = (u16*)(POOL + 27136);  // [2][256*32] swizzled
    __shared__ float smu[32], srs[32];
    int t = threadIdx.x;
    int lane = t & 63, wv = t >> 6;
    int lane15 = lane & 15, quad = lane >> 4;
    int ks = blockIdx.x, b = blockIdx.y;
    int lbase = ks * 512;
    int m0 = (wv & 1) * 64, n0 = (wv >> 1) * 128;

    // staging geometry: lv = l-quad owned (l = 4lv..4lv+3), rw = channel row
    int lv = t & 7, rw = t >> 3;     // rw 0..31; wave covers 8 consecutive rows

    // logits constants: per wave 2 heads, A-frags + Swg/Cb in registers
    bf16x8 af[2];
    float swr[2][4], cbr[2][4];
    #pragma unroll
    for (int s = 0; s < 2; s++) {
        int h = wv * 2 + s;
        af[s] = *(const bf16x8*)(wc + (size_t)(h * 16 + lane15) * DH + quad * 8);
        #pragma unroll
        for (int r = 0; r < 4; r++) {
            int hq = h * 16 + quad * 4 + r;
            swr[s][r] = Swg[hq];
            cbr[s][r] = Cb[hq];
        }
    }

    // coalesced base: 8 lanes x 16 B cover one channel-row's 128 B
    const float* xB = x + ((size_t)b * C_) * L_ + lbase + lv * 4;

    float4 fr[8];       // fp32 prefetch: pass p -> channel p*32+rw, l = 4lv..4lv+3
    uint2 pr2[8];       // packed bf16 (4 l per pass)
    auto loadregs = [&](int k) {
        #pragma unroll
        for (int p = 0; p < 8; p++)
            fr[p] = *(const float4*)(xB + (size_t)(p * 32 + rw) * L_ + k * 32);
    };
    auto cvtregs = [&]() {
        #pragma unroll
        for (int p = 0; p < 8; p++) {
            pr2[p].x = pk2(f32_to_bf16(fr[p].x), f32_to_bf16(fr[p].y));
            pr2[p].y = pk2(f32_to_bf16(fr[p].z), f32_to_bf16(fr[p].w));
        }
    };
    // XT [l][c]: 4 scalar u16 stores per pass (32 total, like R1; no shuffles)
    auto write_xt = [&]() {
        #pragma unroll
        for (int p = 0; p < 8; p++) {
            int c = p * 32 + rw;
            XT[(4 * lv + 0) * 264 + c] = (u16)(pr2[p].x & 0xffffu);
            XT[(4 * lv + 1) * 264 + c] = (u16)(pr2[p].x >> 16);
            XT[(4 * lv + 2) * 264 + c] = (u16)(pr2[p].y & 0xffffu);
            XT[(4 * lv + 3) * 264 + c] = (u16)(pr2[p].y >> 16);
        }
    };
    // XC [c][l] swizzled: granule g2 = lv>>1 holds l 8g2..8g2+7; uint2 = half
    // granule (hl). Same physical layout the GEMM reads (R1-compatible).
    auto write_xc = [&](int buf) {
        int g2 = lv >> 1, hl = (lv & 1) * 4;
        #pragma unroll
        for (int p = 0; p < 8; p++) {
            int c = p * 32 + rw;
            *(uint2*)&XCb[buf * 8192 + c * 32 + ((g2 ^ (c & 3)) * 8) + hl] = pr2[p];
        }
    };

    f32x4 acc[4][8];
    #pragma unroll
    for (int i = 0; i < 4; i++)
        #pragma unroll
        for (int j = 0; j < 8; j++) {
            f32x4 z = {0.f, 0.f, 0.f, 0.f};
            acc[i][j] = z;
        }
    float se[2][4] = {}, sm[2][4] = {};

    int l_loc = t >> 3, g = t & 7;     // stats assignment: 8 threads per l

    loadregs(0);
    cvtregs();
    write_xt();
    write_xc(0);
    loadregs(1);
    __syncthreads();

    for (int k = 0; k < 16; k++) {
        int cur = k & 1;

        // ---- stats phase: mu/rs for chunk k from XT (bf16-sourced) ----
        {
            const u16* row = XT + l_loc * 264 + g * 32;
            float s = 0.f, q = 0.f;
            #pragma unroll
            for (int j = 0; j < 4; j++) {
                uint4 v = *(const uint4*)(row + j * 8);
                u32 ww[4] = {v.x, v.y, v.z, v.w};
                #pragma unroll
                for (int e = 0; e < 4; e++) {
                    float f0 = __uint_as_float(ww[e] << 16);
                    float f1 = __uint_as_float(ww[e] & 0xffff0000u);
                    s += f0 + f1;
                    q += f0 * f0 + f1 * f1;
                }
            }
            #pragma unroll
            for (int off = 1; off < 8; off <<= 1) {
                s += __shfl_xor(s, off);
                q += __shfl_xor(q, off);
            }
            if (g == 0) {
                float mm = s * (1.f / C_);
                float vv = fmaxf(q * (1.f / C_) - mm * mm, 0.f) + EPS_;
                smu[l_loc] = mm;
                srs[l_loc] = rsqrtf(vv);
            }
        }
        __syncthreads();   // smu/srs ready

        // ---- logits phase: MFMA over XT -> exp -> EA (+ running sums) ----
        #pragma unroll
        for (int half = 0; half < 2; half++) {
            float m_l = smu[half * 16 + lane15];
            float r_l = srs[half * 16 + lane15];
            #pragma unroll
            for (int s = 0; s < 2; s++) {
                int h = wv * 2 + s;
                bf16x8 bfrag = *(const bf16x8*)(XT + (half * 16 + lane15) * 264 + h * DH + quad * 8);
                f32x4 z = {0.f, 0.f, 0.f, 0.f};
                f32x4 c4 = __builtin_amdgcn_mfma_f32_16x16x32_bf16(af[s], bfrag, z, 0, 0, 0);
                #pragma unroll
                for (int r = 0; r < 4; r++) {
                    float logit = r_l * (c4[r] - m_l * swr[s][r]) + cbr[s][r];
                    float e = __expf(logit);     // logits ~N(0,1): no max-sub needed
                    float ers = e * r_l;
                    EA[(h * 16 + quad * 4 + r) * 40 + half * 16 + lane15] = f32_to_bf16(ers);
                    se[s][r] += e;
                    sm[s][r] += ers * m_l;
                }
            }
        }
        __syncthreads();   // EA complete; XT reads done -> XT free

        // ---- staging for chunk k+1 + GEMM chunk k ----
        if (k < 15) { cvtregs(); write_xt(); write_xc(cur ^ 1); }
        if (k < 14) loadregs(k + 2);

        bf16x8 a[4];
        #pragma unroll
        for (int i = 0; i < 4; i++)
            a[i] = *(const bf16x8*)&EA[(m0 + i * 16 + lane15) * 40 + quad * 8];
        #pragma unroll
        for (int j = 0; j < 8; j++) {
            int row = n0 + j * 16 + lane15;
            bf16x8 bbj = *(const bf16x8*)&XCb[cur * 8192 + row * 32 + ((quad ^ (row & 3)) * 8)];
            #pragma unroll
            for (int i = 0; i < 4; i++)
                acc[i][j] = __builtin_amdgcn_mfma_f32_16x16x32_bf16(a[i], bbj, acc[i][j], 0, 0, 0);
        }
        __syncthreads();   // GEMM reads done -> EA/XC[cur] free for next iter
    }

    // ---- epilogue 1: Praw (acc) -> LDS bf16 [hq][c], pitch 264 ----
    u16* const P = (u16*)POOL;   // reuses the whole pool (all readers done)
    #pragma unroll
    for (int i = 0; i < 4; i++)
        #pragma unroll
        for (int j = 0; j < 8; j++) {
            int row = m0 + i * 16 + quad * 4;
            int col = n0 + j * 16 + lane15;
            #pragma unroll
            for (int r = 0; r < 4; r++)
                P[(row + r) * 264 + col] = f32_to_bf16(acc[i][j][r]);
        }
    __syncthreads();

    // ---- epilogue 2: Apart[hq][d] = sum_c VGc[hd][c] * Praw[hq][c] ----
    float* ApB = Apart + (((size_t)ks * B_ + b) * HQ) * DH;
    #pragma unroll
    for (int s = 0; s < 2; s++) {
        int h = wv * 2 + s;
        #pragma unroll
        for (int dt = 0; dt < 2; dt++) {
            f32x4 c2 = {0.f, 0.f, 0.f, 0.f};
            #pragma unroll
            for (int kk = 0; kk < 8; kk++) {
                bf16x8 a = *(const bf16x8*)&P[(h * 16 + lane15) * 264 + kk * 32 + quad * 8];
                bf16x8 vg = *(const bf16x8*)(VGc + (size_t)(h * DH + dt * 16 + lane15) * C_ + kk * 32 + quad * 8);
                c2 = __builtin_amdgcn_mfma_f32_16x16x32_bf16(a, vg, c2, 0, 0, 0);
            }
            #pragma unroll
            for (int r = 0; r < 4; r++)
                ApB[(size_t)(h * 16 + quad * 4 + r) * DH + dt * 16 + lane15] = c2[r];
        }
    }

    // ---- softmax partial sums: reduce over lane15, one plain store per row ----
    #pragma unroll
    for (int s = 0; s < 2; s++)
        #pragma unroll
        for (int r = 0; r < 4; r++) {
            float v = se[s][r], w = sm[s][r];
            #pragma unroll
            for (int off = 1; off < 16; off <<= 1) {
                v += __shfl_xor(v, off);
                w += __shfl_xor(w, off);
            }
            if (lane15 == 0) {
                int row = b * HQ + (wv * 2 + s) * 16 + quad * 4 + r;
                DenP[ks * (B_ * HQ) + row] = v;
                SnuP[ks * (B_ * HQ) + row] = w;
            }
        }
}

// ---------------------------------------------------------------------------
// k_reduce: A[b][hq][d] = (sum_s Apart - SnuTot*Wg1[hd]) / DenTot
//           + Wb1[hd] + val_b[hd]       (beta term: se/den == 1)
// ---------------------------------------------------------------------------
__global__ __launch_bounds__(256) void k_reduce(
    const float* __restrict__ Apart, const float* __restrict__ DenP,
    const float* __restrict__ SnuP, const float* __restrict__ Wg1,
    const float* __restrict__ Wb1, const float* __restrict__ val_b,
    float* __restrict__ A)
{
    __shared__ float sden[32], ssnu[32];
    int t = threadIdx.x;
    int q4 = blockIdx.x, b = blockIdx.y;
    int hq0 = q4 * 32;
    if (t < 32) {
        int row = b * HQ + hq0 + t;
        float d = 0.f, sn = 0.f;
        #pragma unroll
        for (int s = 0; s < 8; s++) {
            d  += DenP[s * (B_ * HQ) + row];
            sn += SnuP[s * (B_ * HQ) + row];
        }
        sden[t] = d;
        ssnu[t] = sn;
    }
    __syncthreads();
    #pragma unroll
    for (int i = 0; i < 4; i++) {
        int idx = i * 256 + t;
        int r32 = idx >> 5, d = idx & 31;
        int hq = hq0 + r32;
        float v = 0.f;
        #pragma unroll
        for (int s = 0; s < 8; s++)
            v += Apart[(((size_t)s * B_ + b) * HQ + hq) * DH + d];
        int hd = (hq >> 4) * DH + d;
        A[((size_t)b * HQ + hq) * DH + d] =
            (v - ssnu[r32] * Wg1[hd]) / sden[r32] + Wb1[hd] + val_b[hd];
    }
}

// ---------------------------------------------------------------------------
// k_final: out[b][f] = sum_j A[b][j]*fin_w[f][j] + fin_b[f]
// grid (32,16), block 256; k-split atomicAdd (out pre-zeroed).
// ---------------------------------------------------------------------------
__global__ __launch_bounds__(256) void k_final(
    const float* __restrict__ A, const float* __restrict__ fin_w,
    const float* __restrict__ fin_b, float* __restrict__ out)
{
    __shared__ float At[64 * 129];
    __shared__ float Fw[32 * 129];
    int t = threadIdx.x;
    int kc = blockIdx.x, ft = blockIdx.y;
    int k0 = kc * 128;

    #pragma unroll
    for (int w = 0; w < 8; w++) {
        int s = t + w * 256;
        int row = s >> 5, seg = s & 31;
        float4 v = *(const float4*)(A + (size_t)row * 4096 + k0 + seg * 4);
        const float* pf = (const float*)&v;
        #pragma unroll
        for (int e = 0; e < 4; e++) At[row * 129 + seg * 4 + e] = pf[e];
    }
    #pragma unroll
    for (int w = 0; w < 4; w++) {
        int s = t + w * 256;
        int row = s >> 5, seg = s & 31;
        float4 v = *(const float4*)(fin_w + (size_t)(ft * 32 + row) * 4096 + k0 + seg * 4);
        const float* pf = (const float*)&v;
        #pragma unroll
        for (int e = 0; e < 4; e++) Fw[row * 129 + seg * 4 + e] = pf[e];
    }
    __syncthreads();

    int tb = t >> 3, tf = t & 7;
    float acc[2][4];
    #pragma unroll
    for (int e = 0; e < 2; e++)
        #pragma unroll
        for (int j = 0; j < 4; j++) acc[e][j] = 0.f;

    for (int k = 0; k < 128; k++) {
        float a0 = At[(tb * 2) * 129 + k];
        float a1 = At[(tb * 2 + 1) * 129 + k];
        #pragma unroll
        for (int j = 0; j < 4; j++) {
            float f = Fw[(tf * 4 + j) * 129 + k];
            acc[0][j] += a0 * f;
            acc[1][j] += a1 * f;
        }
    }
    #pragma unroll
    for (int e = 0; e < 2; e++) {
        int brow = tb * 2 + e;
        #pragma unroll
        for (int j = 0; j < 4; j++) {
            int f = ft * 32 + tf * 4 + j;
            float v = acc[e][j];
            if (kc == 0) v += fin_b[f];
            atomicAdd(&out[(size_t)brow * FHN + f], v);
        }
    }
}

extern "C" void kernel_launch(void* const* d_in, const int* in_sizes, int n_in,
                              void* d_out, int out_size, void* d_ws, size_t ws_size,
                              hipStream_t stream) {
    const float* x      = (const float*)d_in[0];
    const float* gamma  = (const float*)d_in[1];
    const float* beta   = (const float*)d_in[2];
    const float* attn_w = (const float*)d_in[3];
    const float* val_w  = (const float*)d_in[4];
    const float* val_b  = (const float*)d_in[5];
    const float* fin_w  = (const float*)d_in[6];
    const float* fin_b  = (const float*)d_in[7];
    float* out = (float*)d_out;
    char* ws = (char*)d_ws;

    u16*   wc    = (u16*)(ws + WS_WC);
    float* Swg   = (float*)(ws + WS_SWG);
    float* Cb    = (float*)(ws + WS_CB);
    u16*   VGc   = (u16*)(ws + WS_VGC);
    float* Wg1   = (float*)(ws + WS_WG1);
    float* Wb1   = (float*)(ws + WS_WB1);
    float* DenP  = (float*)(ws + WS_DENP);
    float* SnuP  = (float*)(ws + WS_SNUP);
    float* A     = (float*)(ws + WS_A);
    float* Apart = (float*)(ws + WS_APART);

    hipMemsetAsync(out, 0, (size_t)B_ * FHN * sizeof(float), stream);

    k_prep<<<dim3(1), dim3(256), 0, stream>>>(attn_w, gamma, beta, wc, Swg, Cb);
    k_prepv<<<dim3(64), dim3(256), 0, stream>>>(val_w, gamma, beta, VGc, Wg1, Wb1);
    k_fused<<<dim3(8, 64), dim3(256), 0, stream>>>(x, wc, Swg, Cb, VGc, Apart,
                                                   DenP, SnuP);
    k_reduce<<<dim3(4, 64), dim3(256), 0, stream>>>(Apart, DenP, SnuP, Wg1, Wb1,
                                                    val_b, A);
    k_final<<<dim3(32, 16), dim3(256), 0, stream>>>(A, fin_w, fin_b, out);
}